// Round 15
// baseline (646.140 us; speedup 1.0000x reference)
//
#include <hip/hip_runtime.h>
#include <stdint.h>

// ---------------- problem constants ----------------
#define N_USERS 100000
#define N_ITEMS 200000
#define NTOT    300000
#define DIM     64
#define NNZ     4000000

// output layout (floats)
#define OUT_I    25600000
#define OUT_CLU  76800000
#define OUT_CLI  83200000

#define COLMASK  0x7FFFFu

// bucketed CSR build
#define RPB   1024
#define NB    ((NTOT + RPB - 1) / RPB)  // 293
#define TILE  4096
#define NBT   ((NNZ + TILE - 1) / TILE) // 977
#define BCAP  20480
#define HCAP  2500000

typedef float floatx4 __attribute__((ext_vector_type(4)));
typedef unsigned short ushortx4 __attribute__((ext_vector_type(4)));

// ---------------- threefry2x32 (20 rounds) ----------------
__host__ __device__ __forceinline__ void tf2x32(uint32_t k0, uint32_t k1,
                                                uint32_t x0, uint32_t x1,
                                                uint32_t& o0, uint32_t& o1) {
  uint32_t ks2 = k0 ^ k1 ^ 0x1BD11BDAu;
#define TFR(r) { x0 += x1; x1 = (x1 << (r)) | (x1 >> (32 - (r))); x1 ^= x0; }
  x0 += k0; x1 += k1;
  TFR(13) TFR(15) TFR(26) TFR(6)
  x0 += k1;  x1 += ks2 + 1u;
  TFR(17) TFR(29) TFR(16) TFR(24)
  x0 += ks2; x1 += k0 + 2u;
  TFR(13) TFR(15) TFR(26) TFR(6)
  x0 += k0;  x1 += k1 + 3u;
  TFR(17) TFR(29) TFR(16) TFR(24)
  x0 += k1;  x1 += ks2 + 4u;
  TFR(13) TFR(15) TFR(26) TFR(6)
  x0 += ks2; x1 += k0 + 5u;
#undef TFR
  o0 = x0; o1 = x1;
}

__device__ __forceinline__ uint32_t rnd_bits(uint32_t k0, uint32_t k1, uint32_t j) {
  uint32_t a, b;
  tf2x32(k0, k1, 0u, j, a, b);
  return a ^ b;
}

__device__ __forceinline__ float u01f(uint32_t bits) {
  return __uint_as_float((bits >> 9) | 0x3f800000u) - 1.0f;
}

__device__ __forceinline__ unsigned short f2bf(float f) {
  uint32_t u = __float_as_uint(f);
  return (unsigned short)((u + 0x7FFFu + ((u >> 16) & 1u)) >> 16);
}

// branchless single-precision erfinv (Giles 2010)
__device__ __forceinline__ float erfinv_giles(float x) {
  float w = -__logf((1.0f - x) * (1.0f + x));
  float wc = w - 2.5f;
  float p1 = 2.81022636e-08f;
  p1 = fmaf(p1, wc, 3.43273939e-07f);
  p1 = fmaf(p1, wc, -3.5233877e-06f);
  p1 = fmaf(p1, wc, -4.39150654e-06f);
  p1 = fmaf(p1, wc, 0.00021858087f);
  p1 = fmaf(p1, wc, -0.00125372503f);
  p1 = fmaf(p1, wc, -0.00417768164f);
  p1 = fmaf(p1, wc, 0.246640727f);
  p1 = fmaf(p1, wc, 1.50140941f);
  float wt = __builtin_sqrtf(w) - 3.0f;
  float p2 = -0.000200214257f;
  p2 = fmaf(p2, wt, 0.000100950558f);
  p2 = fmaf(p2, wt, 0.00134934322f);
  p2 = fmaf(p2, wt, -0.00367342844f);
  p2 = fmaf(p2, wt, 0.00573950773f);
  p2 = fmaf(p2, wt, -0.0076224613f);
  p2 = fmaf(p2, wt, 0.00943887047f);
  p2 = fmaf(p2, wt, 1.00167406f);
  p2 = fmaf(p2, wt, 2.83297682f);
  float p = (w < 5.0f) ? p1 : p2;
  return p * x;
}

// ---------------- scalar row-extent load (proven form) ----------------
__device__ __forceinline__ void sload_se(const int2* p, int& s, int& e) {
  uint64_t r;
  asm volatile("s_load_dwordx2 %0, %1, 0x0\n\t"
               "s_waitcnt lgkmcnt(0)"
               : "=&s"(r) : "s"(p));
  s = (int)(uint32_t)r;
  e = (int)(uint32_t)(r >> 32);
}

// ---------------- phase 1 (merged): bin edges + init hop-0 outputs ----------
__global__ __launch_bounds__(256) void k_bin_init(const int* __restrict__ rows,
                                                  const int* __restrict__ cols,
                                                  const float* __restrict__ adjv,
                                                  int* __restrict__ gcount,
                                                  uint2* __restrict__ staging,
                                                  const float* __restrict__ ue,
                                                  const float* __restrict__ ie,
                                                  float* __restrict__ out,
                                                  unsigned short* __restrict__ T0,
                                                  uint32_t ke00, uint32_t ke01,
                                                  uint32_t ke10, uint32_t ke11,
                                                  uint32_t ke20, uint32_t ke21) {
  __shared__ int hist[NB];
  __shared__ int gb[NB];
  if (blockIdx.x >= NBT) {
    int t = (blockIdx.x - NBT) * 256 + threadIdx.x;
    if (t >= NTOT * DIM / 4) return;
    int j = t * 4;
    int r = j >> 6;
    int d = j & 63;
    floatx4 v = (r < N_USERS) ? *reinterpret_cast<const floatx4*>(ue + j)
                              : *reinterpret_cast<const floatx4*>(ie + (j - N_USERS * DIM));
    int o = (r < N_USERS) ? (r * 256 + d) : (OUT_I + (r - N_USERS) * 256 + d);
    __builtin_nontemporal_store(v, reinterpret_cast<floatx4*>(out + o));
    ushortx4 bv;
    bv.x = f2bf(v.x); bv.y = f2bf(v.y); bv.z = f2bf(v.z); bv.w = f2bf(v.w);
    *reinterpret_cast<ushortx4*>(T0 + j) = bv;
    return;
  }
  int t = threadIdx.x;
  for (int i = t; i < NB; i += 256) hist[i] = 0;
  __syncthreads();
  int base = blockIdx.x * TILE;

  uint32_t recx[16];
  float    recy[16];
  uint32_t bl[16];

#pragma unroll
  for (int i = 0; i < 16; i++) {
    int e = base + i * 256 + t;
    bl[i] = 0xFFFFFFFFu;
    if (e < NNZ) {
      int r = rows[e];
      uint32_t c = (uint32_t)cols[e];
      uint32_t m0 = rnd_bits(ke00, ke01, (uint32_t)e) >> 31;
      uint32_t m1 = rnd_bits(ke10, ke11, (uint32_t)e) >> 31;
      uint32_t m2 = rnd_bits(ke20, ke21, (uint32_t)e) >> 31;
      recx[i] = c | (m0 << 19) | (m1 << 20) | (m2 << 21) | ((uint32_t)(r & (RPB - 1)) << 22);
      recy[i] = adjv[e] * 2.0f;
      int b = r >> 10;
      int lp = atomicAdd(&hist[b], 1);
      bl[i] = ((uint32_t)b << 13) | (uint32_t)lp;
    }
  }
  __syncthreads();
  for (int i = t; i < NB; i += 256) {
    int c = hist[i];
    gb[i] = c ? atomicAdd(&gcount[i], c) : 0;
  }
  __syncthreads();
#pragma unroll
  for (int i = 0; i < 16; i++) {
    if (bl[i] != 0xFFFFFFFFu) {
      int b  = (int)(bl[i] >> 13);
      int lp = (int)(bl[i] & 0x1FFFu);
      staging[(size_t)b * BCAP + gb[b] + lp] = make_uint2(recx[i], __float_as_uint(recy[i]));
    }
  }
}

// ---------------- phase 2: per-bucket count/scan/reserve/scatter ------------
__global__ __launch_bounds__(256) void k_place3(const int* __restrict__ gcount,
                                                const uint2* __restrict__ staging,
                                                uint2* __restrict__ packed3,
                                                int2* __restrict__ rowse3,
                                                int* __restrict__ gtail) {
  __shared__ int cnt[3][RPB];
  __shared__ int off[3][RPB];
  __shared__ int sm[256];
  __shared__ int gbh[3];
  int b = blockIdx.x;
  int t = threadIdx.x;
  int r0 = b << 10;
  for (int j = t; j < RPB; j += 256) { cnt[0][j] = 0; cnt[1][j] = 0; cnt[2][j] = 0; }
  __syncthreads();
  int ln = gcount[b];
  const uint2* run = staging + (size_t)b * BCAP;

  for (int i = t; i < ln; i += 256) {
    uint32_t w = run[i].x;
    int rl = (int)(w >> 22);
    if (w & (1u << 19)) atomicAdd(&cnt[0][rl], 1);
    if (w & (1u << 20)) atomicAdd(&cnt[1][rl], 1);
    if (w & (1u << 21)) atomicAdd(&cnt[2][rl], 1);
  }
  __syncthreads();

  for (int h = 0; h < 3; h++) {
    int j0 = t * 4;
    int c0 = cnt[h][j0], c1 = cnt[h][j0 + 1], c2 = cnt[h][j0 + 2], c3 = cnt[h][j0 + 3];
    int e0 = (c0 + 1) & ~1, e1 = (c1 + 1) & ~1, e2 = (c2 + 1) & ~1, e3 = (c3 + 1) & ~1;
    int s4 = e0 + e1 + e2 + e3;
    sm[t] = s4;
    __syncthreads();
    for (int o2 = 1; o2 < 256; o2 <<= 1) {
      int y = (t >= o2) ? sm[t - o2] : 0;
      __syncthreads();
      sm[t] += y;
      __syncthreads();
    }
    int ex = sm[t] - s4;
    off[h][j0]     = ex;
    off[h][j0 + 1] = ex + e0;
    off[h][j0 + 2] = ex + e0 + e1;
    off[h][j0 + 3] = ex + e0 + e1 + e2;
    if (t == 255) gbh[h] = atomicAdd(&gtail[h], sm[255]);
    __syncthreads();
  }

  int nr = min(RPB, NTOT - r0);
  for (int h = 0; h < 3; h++) {
    int gb = gbh[h];
    for (int j = t; j < RPB; j += 256) {
      int raw = cnt[h][j];
      int start = gb + off[h][j];
      off[h][j] = start;
      if (j < nr) {
        rowse3[h * NTOT + r0 + j] = make_int2(start, start + ((raw + 1) & ~1));
        if (raw & 1) packed3[(size_t)h * HCAP + start + raw] = make_uint2(0u, 0u);
      }
    }
  }
  __syncthreads();

  for (int i = t; i < ln; i += 256) {
    uint2 rec = run[i];
    int rl = (int)(rec.x >> 22);
    uint2 orec = make_uint2(rec.x & COLMASK, rec.y);
    if (rec.x & (1u << 19)) { int p = atomicAdd(&off[0][rl], 1); packed3[0 * (size_t)HCAP + p] = orec; }
    if (rec.x & (1u << 20)) { int p = atomicAdd(&off[1][rl], 1); packed3[1 * (size_t)HCAP + p] = orec; }
    if (rec.x & (1u << 21)) { int p = atomicAdd(&off[2][rl], 1); packed3[2 * (size_t)HCAP + p] = orec; }
  }
}

// ---------------- fused hop: SpMM + LN + dropout + perturb + outputs --------
// one 64-lane wave per row. Records loaded PER-LANE (lane k holds record k;
// one coalesced v_load + ONE vmcnt wait per 64 records), then broadcast to
// the dual-edge consumers via __shfl (ds_bpermute with per-lane src index).
// Dual-edge gather: lanes 0-31 edge even, lanes 32-63 edge odd; each lane
// loads a dword of the bf16 table = 2 dims.
template <int HOP>
__global__ __launch_bounds__(256) void k_hop(const int2* __restrict__ rowse,
                                             const uint2* __restrict__ packed,
                                             const unsigned short* __restrict__ Tin,
                                             unsigned short* __restrict__ Tout,
                                             const float* __restrict__ gamma,
                                             const float* __restrict__ beta,
                                             float* __restrict__ out,
                                             uint32_t km0, uint32_t km1,
                                             uint32_t kp0, uint32_t kp1) {
  int lane = threadIdx.x & 63;
  int hi = lane >> 5;          // 0 for lanes 0-31, 1 for lanes 32-63
  int l31 = lane & 31;
  int r = __builtin_amdgcn_readfirstlane((int)(blockIdx.x * blockDim.x + threadIdx.x) >> 6);
  if (r >= NTOT) return;
  int s, e;
  sload_se(rowse + r, s, e);
  s = max(s, 0);
  e = min(e, HCAP);
  const uint32_t* __restrict__ T32 = (const uint32_t*)Tin;

  float lo0 = 0.0f, hi0 = 0.0f, lo1 = 0.0f, hi1 = 0.0f;

  for (int base = s; base < e; base += 64) {
    int m = min(e - base, 64);              // uniform, even
    int li = (lane < m) ? lane : 0;
    uint2 rec = packed[base + li];          // lane k holds record k (1 vm wait)
    int pairs = m >> 1;
    int i = 0;
    for (; i + 1 < pairs; i += 2) {
      int src0 = 2 * i + hi;
      int src1 = 2 * i + 2 + hi;
      uint32_t c0 = (uint32_t)__shfl((int)rec.x, src0, 64);
      uint32_t v0 = (uint32_t)__shfl((int)rec.y, src0, 64);
      uint32_t c1 = (uint32_t)__shfl((int)rec.x, src1, 64);
      uint32_t v1 = (uint32_t)__shfl((int)rec.y, src1, 64);
      uint32_t u0 = T32[c0 * 32 + l31];
      uint32_t u1 = T32[c1 * 32 + l31];
      float f0 = __uint_as_float(v0);
      float f1 = __uint_as_float(v1);
      lo0 = fmaf(f0, __uint_as_float(u0 << 16), lo0);
      hi0 = fmaf(f0, __uint_as_float(u0 & 0xFFFF0000u), hi0);
      lo1 = fmaf(f1, __uint_as_float(u1 << 16), lo1);
      hi1 = fmaf(f1, __uint_as_float(u1 & 0xFFFF0000u), hi1);
    }
    for (; i < pairs; i++) {
      int src0 = 2 * i + hi;
      uint32_t c0 = (uint32_t)__shfl((int)rec.x, src0, 64);
      uint32_t v0 = (uint32_t)__shfl((int)rec.y, src0, 64);
      uint32_t u0 = T32[c0 * 32 + l31];
      float f0 = __uint_as_float(v0);
      lo0 = fmaf(f0, __uint_as_float(u0 << 16), lo0);
      hi0 = fmaf(f0, __uint_as_float(u0 & 0xFFFF0000u), hi0);
    }
  }

  float alo = lo0 + lo1;
  float ahi = hi0 + hi1;
  // combine even-edge (lanes<32) and odd-edge (lanes>=32) partial sums
  alo += __shfl_xor(alo, 32, 64);
  ahi += __shfl_xor(ahi, 32, 64);
  // redistribute: lane d owns dim d ( = slot d&1 of lane d>>1 )
  float xlo = __shfl(alo, lane >> 1, 64);
  float xhi = __shfl(ahi, lane >> 1, 64);
  float x = (lane & 1) ? xhi : xlo;

  // layer norm: fused dual reduction (sum, sumsq) over the wave
  float s1 = x, s2 = x * x;
#pragma unroll
  for (int mm = 32; mm >= 1; mm >>= 1) {
    s1 += __shfl_xor(s1, mm, 64);
    s2 += __shfl_xor(s2, mm, 64);
  }
  float mu = s1 * (1.0f / 64.0f);
  float var = fmaxf(s2 * (1.0f / 64.0f) - mu * mu, 0.0f);
  x = (x - mu) * rsqrtf(var + 1e-5f) * gamma[lane] + beta[lane];

  // message dropout: keep iff uniform >= 0.1
  uint32_t j = (uint32_t)(r * DIM + lane);
  float um = u01f(rnd_bits(km0, km1, j));
  const float INV_KEEP = (float)(1.0 / 0.9);
  x = x * ((um >= 0.1f) ? INV_KEEP : 0.0f);

  // perturbation: normal via erfinv of uniform(lo, 1), row-normalized
  float un = u01f(rnd_bits(kp0, kp1, j));
  const float LO = __uint_as_float(0xBF7FFFFFu);
  float val = un * 2.0f + LO;
  float nz = 0x1.6a09e6p+0f * erfinv_giles(val);
  float q2 = nz * nz;
#pragma unroll
  for (int mm = 32; mm >= 1; mm >>= 1) q2 += __shfl_xor(q2, mm, 64);
  float nrm = __builtin_sqrtf(q2);
  float nh = nz / (nrm + 1e-12f);
  float sg = (x > 0.0f) ? 1.0f : ((x < 0.0f) ? -1.0f : 0.0f);
  x = x + sg * nh * 0.03f;

  // next-hop bf16 table (cached; skipped at last hop) + fp32 outputs (NT)
  if (HOP < 2) Tout[r * DIM + lane] = f2bf(x);
  constexpr int h1 = HOP + 1;
  if (r < N_USERS) {
    __builtin_nontemporal_store(x, &out[r * 256 + h1 * 64 + lane]);
    if (HOP == 0) __builtin_nontemporal_store(x, &out[OUT_CLU + r * 64 + lane]);
  } else {
    int i = r - N_USERS;
    __builtin_nontemporal_store(x, &out[OUT_I + i * 256 + h1 * 64 + lane]);
    if (HOP == 0) __builtin_nontemporal_store(x, &out[OUT_CLI + i * 64 + lane]);
  }
}

// ---------------- launch ----------------
extern "C" void kernel_launch(void* const* d_in, const int* in_sizes, int n_in,
                              void* d_out, int out_size, void* d_ws, size_t ws_size,
                              hipStream_t stream) {
  (void)in_sizes; (void)n_in; (void)out_size; (void)ws_size;
  const float* ue    = (const float*)d_in[0];
  const float* ie    = (const float*)d_in[1];
  const float* adjv  = (const float*)d_in[2];
  const float* gamma = (const float*)d_in[3];
  const float* beta  = (const float*)d_in[4];
  const int*   adji  = (const int*)d_in[5];
  const int* rows = adji;
  const int* cols = adji + NNZ;
  float* out = (float*)d_out;

  char* ws = (char*)d_ws;
  size_t off = 0;
  auto alloc = [&](size_t bytes) -> void* {
    void* p = ws + off;
    off += (bytes + 255) & ~(size_t)255;
    return p;
  };
  unsigned short* TA = (unsigned short*)alloc(sizeof(short) * NTOT * DIM);
  unsigned short* TB = (unsigned short*)alloc(sizeof(short) * NTOT * DIM);
  int*   gcount  = (int*)alloc(sizeof(int) * NB);
  int*   gtail   = (int*)alloc(sizeof(int) * 4);
  int2*  rowse3  = (int2*)alloc(sizeof(int2) * 3 * NTOT);
  uint2* staging = (uint2*)alloc(sizeof(uint2) * (size_t)NB * BCAP);
  uint2* packed3 = (uint2*)alloc(sizeof(uint2) * 3 * (size_t)HCAP);

  uint32_t K[3][6];
  for (uint32_t h = 0; h < 3; h++) {
    uint32_t h0, h1;
    tf2x32(0u, 42u, 0u, h, h0, h1);
    tf2x32(h0, h1, 0u, 0u, K[h][0], K[h][1]);  // ke
    tf2x32(h0, h1, 0u, 1u, K[h][2], K[h][3]);  // km
    tf2x32(h0, h1, 0u, 2u, K[h][4], K[h][5]);  // kp
  }

  (void)hipMemsetAsync(gcount, 0, sizeof(int) * NB, stream);
  (void)hipMemsetAsync(gtail, 0, sizeof(int) * 4, stream);

  const int nbInit = (NTOT * DIM / 4 + 255) / 256;
  k_bin_init<<<NBT + nbInit, 256, 0, stream>>>(rows, cols, adjv, gcount, staging,
                                               ue, ie, out, TA,
                                               K[0][0], K[0][1], K[1][0], K[1][1],
                                               K[2][0], K[2][1]);
  k_place3<<<NB, 256, 0, stream>>>(gcount, staging, packed3, rowse3, gtail);

  const int nbH = (NTOT * 64 + 255) / 256;
  k_hop<0><<<nbH, 256, 0, stream>>>(rowse3 + 0 * NTOT, packed3 + 0 * (size_t)HCAP,
                                    TA, TB, gamma, beta, out,
                                    K[0][2], K[0][3], K[0][4], K[0][5]);
  k_hop<1><<<nbH, 256, 0, stream>>>(rowse3 + 1 * NTOT, packed3 + 1 * (size_t)HCAP,
                                    TB, TA, gamma, beta, out,
                                    K[1][2], K[1][3], K[1][4], K[1][5]);
  k_hop<2><<<nbH, 256, 0, stream>>>(rowse3 + 2 * NTOT, packed3 + 2 * (size_t)HCAP,
                                    TA, nullptr, gamma, beta, out,
                                    K[2][2], K[2][3], K[2][4], K[2][5]);
}

// Round 16
// 634.804 us; speedup vs baseline: 1.0179x; 1.0179x over previous
//
#include <hip/hip_runtime.h>
#include <stdint.h>

// ---------------- problem constants ----------------
#define N_USERS 100000
#define N_ITEMS 200000
#define NTOT    300000
#define DIM     64
#define NNZ     4000000

// output layout (floats)
#define OUT_I    25600000
#define OUT_CLU  76800000
#define OUT_CLI  83200000

#define COLMASK  0x7FFFFu

// bucketed CSR build
#define RPB   1024
#define NB    ((NTOT + RPB - 1) / RPB)  // 293
#define TILE  4096
#define NBT   ((NNZ + TILE - 1) / TILE) // 977
#define BCAP  20480
#define HCAP  2500000

typedef float floatx4 __attribute__((ext_vector_type(4)));
typedef unsigned short ushortx4 __attribute__((ext_vector_type(4)));

// ---------------- threefry2x32 (20 rounds) ----------------
__host__ __device__ __forceinline__ void tf2x32(uint32_t k0, uint32_t k1,
                                                uint32_t x0, uint32_t x1,
                                                uint32_t& o0, uint32_t& o1) {
  uint32_t ks2 = k0 ^ k1 ^ 0x1BD11BDAu;
#define TFR(r) { x0 += x1; x1 = (x1 << (r)) | (x1 >> (32 - (r))); x1 ^= x0; }
  x0 += k0; x1 += k1;
  TFR(13) TFR(15) TFR(26) TFR(6)
  x0 += k1;  x1 += ks2 + 1u;
  TFR(17) TFR(29) TFR(16) TFR(24)
  x0 += ks2; x1 += k0 + 2u;
  TFR(13) TFR(15) TFR(26) TFR(6)
  x0 += k0;  x1 += k1 + 3u;
  TFR(17) TFR(29) TFR(16) TFR(24)
  x0 += k1;  x1 += ks2 + 4u;
  TFR(13) TFR(15) TFR(26) TFR(6)
  x0 += ks2; x1 += k0 + 5u;
#undef TFR
  o0 = x0; o1 = x1;
}

__device__ __forceinline__ uint32_t rnd_bits(uint32_t k0, uint32_t k1, uint32_t j) {
  uint32_t a, b;
  tf2x32(k0, k1, 0u, j, a, b);
  return a ^ b;
}

__device__ __forceinline__ float u01f(uint32_t bits) {
  return __uint_as_float((bits >> 9) | 0x3f800000u) - 1.0f;
}

__device__ __forceinline__ unsigned short f2bf(float f) {
  uint32_t u = __float_as_uint(f);
  return (unsigned short)((u + 0x7FFFu + ((u >> 16) & 1u)) >> 16);
}

// branchless single-precision erfinv (Giles 2010)
__device__ __forceinline__ float erfinv_giles(float x) {
  float w = -__logf((1.0f - x) * (1.0f + x));
  float wc = w - 2.5f;
  float p1 = 2.81022636e-08f;
  p1 = fmaf(p1, wc, 3.43273939e-07f);
  p1 = fmaf(p1, wc, -3.5233877e-06f);
  p1 = fmaf(p1, wc, -4.39150654e-06f);
  p1 = fmaf(p1, wc, 0.00021858087f);
  p1 = fmaf(p1, wc, -0.00125372503f);
  p1 = fmaf(p1, wc, -0.00417768164f);
  p1 = fmaf(p1, wc, 0.246640727f);
  p1 = fmaf(p1, wc, 1.50140941f);
  float wt = __builtin_sqrtf(w) - 3.0f;
  float p2 = -0.000200214257f;
  p2 = fmaf(p2, wt, 0.000100950558f);
  p2 = fmaf(p2, wt, 0.00134934322f);
  p2 = fmaf(p2, wt, -0.00367342844f);
  p2 = fmaf(p2, wt, 0.00573950773f);
  p2 = fmaf(p2, wt, -0.0076224613f);
  p2 = fmaf(p2, wt, 0.00943887047f);
  p2 = fmaf(p2, wt, 1.00167406f);
  p2 = fmaf(p2, wt, 2.83297682f);
  float p = (w < 5.0f) ? p1 : p2;
  return p * x;
}

// ---------------- scalar row-extent load (proven form) ----------------
__device__ __forceinline__ void sload_se(const int2* p, int& s, int& e) {
  uint64_t r;
  asm volatile("s_load_dwordx2 %0, %1, 0x0\n\t"
               "s_waitcnt lgkmcnt(0)"
               : "=&s"(r) : "s"(p));
  s = (int)(uint32_t)r;
  e = (int)(uint32_t)(r >> 32);
}

// ---------------- phase 1 (merged): bin edges + init hop-0 outputs ----------
__global__ __launch_bounds__(256) void k_bin_init(const int* __restrict__ rows,
                                                  const int* __restrict__ cols,
                                                  const float* __restrict__ adjv,
                                                  int* __restrict__ gcount,
                                                  uint2* __restrict__ staging,
                                                  const float* __restrict__ ue,
                                                  const float* __restrict__ ie,
                                                  float* __restrict__ out,
                                                  unsigned short* __restrict__ T0,
                                                  uint32_t ke00, uint32_t ke01,
                                                  uint32_t ke10, uint32_t ke11,
                                                  uint32_t ke20, uint32_t ke21) {
  __shared__ int hist[NB];
  __shared__ int gb[NB];
  if (blockIdx.x >= NBT) {
    int t = (blockIdx.x - NBT) * 256 + threadIdx.x;
    if (t >= NTOT * DIM / 4) return;
    int j = t * 4;
    int r = j >> 6;
    int d = j & 63;
    floatx4 v = (r < N_USERS) ? *reinterpret_cast<const floatx4*>(ue + j)
                              : *reinterpret_cast<const floatx4*>(ie + (j - N_USERS * DIM));
    int o = (r < N_USERS) ? (r * 256 + d) : (OUT_I + (r - N_USERS) * 256 + d);
    __builtin_nontemporal_store(v, reinterpret_cast<floatx4*>(out + o));
    ushortx4 bv;
    bv.x = f2bf(v.x); bv.y = f2bf(v.y); bv.z = f2bf(v.z); bv.w = f2bf(v.w);
    *reinterpret_cast<ushortx4*>(T0 + j) = bv;
    return;
  }
  int t = threadIdx.x;
  for (int i = t; i < NB; i += 256) hist[i] = 0;
  __syncthreads();
  int base = blockIdx.x * TILE;

  uint32_t recx[16];
  float    recy[16];
  uint32_t bl[16];

#pragma unroll
  for (int i = 0; i < 16; i++) {
    int e = base + i * 256 + t;
    bl[i] = 0xFFFFFFFFu;
    if (e < NNZ) {
      int r = rows[e];
      uint32_t c = (uint32_t)cols[e];
      uint32_t m0 = rnd_bits(ke00, ke01, (uint32_t)e) >> 31;
      uint32_t m1 = rnd_bits(ke10, ke11, (uint32_t)e) >> 31;
      uint32_t m2 = rnd_bits(ke20, ke21, (uint32_t)e) >> 31;
      recx[i] = c | (m0 << 19) | (m1 << 20) | (m2 << 21) | ((uint32_t)(r & (RPB - 1)) << 22);
      recy[i] = adjv[e] * 2.0f;
      int b = r >> 10;
      int lp = atomicAdd(&hist[b], 1);
      bl[i] = ((uint32_t)b << 13) | (uint32_t)lp;
    }
  }
  __syncthreads();
  for (int i = t; i < NB; i += 256) {
    int c = hist[i];
    gb[i] = c ? atomicAdd(&gcount[i], c) : 0;
  }
  __syncthreads();
#pragma unroll
  for (int i = 0; i < 16; i++) {
    if (bl[i] != 0xFFFFFFFFu) {
      int b  = (int)(bl[i] >> 13);
      int lp = (int)(bl[i] & 0x1FFFu);
      staging[(size_t)b * BCAP + gb[b] + lp] = make_uint2(recx[i], __float_as_uint(recy[i]));
    }
  }
}

// ---------------- phase 2: per-bucket count/scan/reserve/scatter ------------
__global__ __launch_bounds__(256) void k_place3(const int* __restrict__ gcount,
                                                const uint2* __restrict__ staging,
                                                uint2* __restrict__ packed3,
                                                int2* __restrict__ rowse3,
                                                int* __restrict__ gtail) {
  __shared__ int cnt[3][RPB];
  __shared__ int off[3][RPB];
  __shared__ int sm[256];
  __shared__ int gbh[3];
  int b = blockIdx.x;
  int t = threadIdx.x;
  int r0 = b << 10;
  for (int j = t; j < RPB; j += 256) { cnt[0][j] = 0; cnt[1][j] = 0; cnt[2][j] = 0; }
  __syncthreads();
  int ln = gcount[b];
  const uint2* run = staging + (size_t)b * BCAP;

  for (int i = t; i < ln; i += 256) {
    uint32_t w = run[i].x;
    int rl = (int)(w >> 22);
    if (w & (1u << 19)) atomicAdd(&cnt[0][rl], 1);
    if (w & (1u << 20)) atomicAdd(&cnt[1][rl], 1);
    if (w & (1u << 21)) atomicAdd(&cnt[2][rl], 1);
  }
  __syncthreads();

  for (int h = 0; h < 3; h++) {
    int j0 = t * 4;
    int c0 = cnt[h][j0], c1 = cnt[h][j0 + 1], c2 = cnt[h][j0 + 2], c3 = cnt[h][j0 + 3];
    int e0 = (c0 + 1) & ~1, e1 = (c1 + 1) & ~1, e2 = (c2 + 1) & ~1, e3 = (c3 + 1) & ~1;
    int s4 = e0 + e1 + e2 + e3;
    sm[t] = s4;
    __syncthreads();
    for (int o2 = 1; o2 < 256; o2 <<= 1) {
      int y = (t >= o2) ? sm[t - o2] : 0;
      __syncthreads();
      sm[t] += y;
      __syncthreads();
    }
    int ex = sm[t] - s4;
    off[h][j0]     = ex;
    off[h][j0 + 1] = ex + e0;
    off[h][j0 + 2] = ex + e0 + e1;
    off[h][j0 + 3] = ex + e0 + e1 + e2;
    if (t == 255) gbh[h] = atomicAdd(&gtail[h], sm[255]);
    __syncthreads();
  }

  int nr = min(RPB, NTOT - r0);
  for (int h = 0; h < 3; h++) {
    int gb = gbh[h];
    for (int j = t; j < RPB; j += 256) {
      int raw = cnt[h][j];
      int start = gb + off[h][j];
      off[h][j] = start;
      if (j < nr) {
        rowse3[h * NTOT + r0 + j] = make_int2(start, start + ((raw + 1) & ~1));
        if (raw & 1) packed3[(size_t)h * HCAP + start + raw] = make_uint2(0u, 0u);
      }
    }
  }
  __syncthreads();

  for (int i = t; i < ln; i += 256) {
    uint2 rec = run[i];
    int rl = (int)(rec.x >> 22);
    uint2 orec = make_uint2(rec.x & COLMASK, rec.y);
    if (rec.x & (1u << 19)) { int p = atomicAdd(&off[0][rl], 1); packed3[0 * (size_t)HCAP + p] = orec; }
    if (rec.x & (1u << 20)) { int p = atomicAdd(&off[1][rl], 1); packed3[1 * (size_t)HCAP + p] = orec; }
    if (rec.x & (1u << 21)) { int p = atomicAdd(&off[2][rl], 1); packed3[2 * (size_t)HCAP + p] = orec; }
  }
}

// ---------------- fused hop: SpMM + LN + dropout + perturb + outputs --------
// one 64-lane wave per row. Per 64-record chunk: one coalesced per-lane vector
// load into LDS (1 vmcnt wait), then each dual-edge pair does ONE ds_read_b64
// at a half-wave-uniform address (2-way access = free broadcast). Keeps record
// traffic on the vector+LDS path (R13 used the tiny scalar K$; R15's shfl
// chain serialized into the gather addresses).
template <int HOP>
__global__ __launch_bounds__(256) void k_hop(const int2* __restrict__ rowse,
                                             const uint2* __restrict__ packed,
                                             const unsigned short* __restrict__ Tin,
                                             unsigned short* __restrict__ Tout,
                                             const float* __restrict__ gamma,
                                             const float* __restrict__ beta,
                                             float* __restrict__ out,
                                             uint32_t km0, uint32_t km1,
                                             uint32_t kp0, uint32_t kp1) {
  __shared__ uint2 smrec[4][64];
  int lane = threadIdx.x & 63;
  int wid = threadIdx.x >> 6;
  int hi = lane >> 5;          // 0 for lanes 0-31, 1 for lanes 32-63
  int l31 = lane & 31;
  int r = __builtin_amdgcn_readfirstlane((int)(blockIdx.x * blockDim.x + threadIdx.x) >> 6);
  if (r >= NTOT) return;
  int s, e;
  sload_se(rowse + r, s, e);
  s = max(s, 0);
  e = min(e, HCAP);
  const uint32_t* __restrict__ T32 = (const uint32_t*)Tin;

  float lo0 = 0.0f, hi0 = 0.0f, lo1 = 0.0f, hi1 = 0.0f;

  for (int base = s; base < e; base += 64) {
    int m = min(e - base, 64);              // uniform, even
    int li = (lane < m) ? lane : 0;
    smrec[wid][lane] = packed[base + li];   // lane k holds record k (1 vm wait)
    int pairs = m >> 1;
    int i = 0;
    for (; i + 1 < pairs; i += 2) {
      uint2 q0 = smrec[wid][2 * i + hi];        // ds_read_b64, 2-way broadcast
      uint2 q1 = smrec[wid][2 * i + 2 + hi];
      uint32_t u0 = T32[q0.x * 32 + l31];       // cols pre-masked in place3
      uint32_t u1 = T32[q1.x * 32 + l31];
      float f0 = __uint_as_float(q0.y);
      float f1 = __uint_as_float(q1.y);
      lo0 = fmaf(f0, __uint_as_float(u0 << 16), lo0);
      hi0 = fmaf(f0, __uint_as_float(u0 & 0xFFFF0000u), hi0);
      lo1 = fmaf(f1, __uint_as_float(u1 << 16), lo1);
      hi1 = fmaf(f1, __uint_as_float(u1 & 0xFFFF0000u), hi1);
    }
    for (; i < pairs; i++) {
      uint2 q0 = smrec[wid][2 * i + hi];
      uint32_t u0 = T32[q0.x * 32 + l31];
      float f0 = __uint_as_float(q0.y);
      lo0 = fmaf(f0, __uint_as_float(u0 << 16), lo0);
      hi0 = fmaf(f0, __uint_as_float(u0 & 0xFFFF0000u), hi0);
    }
  }

  float alo = lo0 + lo1;
  float ahi = hi0 + hi1;
  // combine even-edge (lanes<32) and odd-edge (lanes>=32) partial sums
  alo += __shfl_xor(alo, 32, 64);
  ahi += __shfl_xor(ahi, 32, 64);
  // redistribute: lane d owns dim d ( = slot d&1 of lane d>>1 )
  float xlo = __shfl(alo, lane >> 1, 64);
  float xhi = __shfl(ahi, lane >> 1, 64);
  float x = (lane & 1) ? xhi : xlo;

  // layer norm: fused dual reduction (sum, sumsq) over the wave
  float s1 = x, s2 = x * x;
#pragma unroll
  for (int mm = 32; mm >= 1; mm >>= 1) {
    s1 += __shfl_xor(s1, mm, 64);
    s2 += __shfl_xor(s2, mm, 64);
  }
  float mu = s1 * (1.0f / 64.0f);
  float var = fmaxf(s2 * (1.0f / 64.0f) - mu * mu, 0.0f);
  x = (x - mu) * rsqrtf(var + 1e-5f) * gamma[lane] + beta[lane];

  // message dropout: keep iff uniform >= 0.1
  uint32_t j = (uint32_t)(r * DIM + lane);
  float um = u01f(rnd_bits(km0, km1, j));
  const float INV_KEEP = (float)(1.0 / 0.9);
  x = x * ((um >= 0.1f) ? INV_KEEP : 0.0f);

  // perturbation: normal via erfinv of uniform(lo, 1), row-normalized
  float un = u01f(rnd_bits(kp0, kp1, j));
  const float LO = __uint_as_float(0xBF7FFFFFu);
  float val = un * 2.0f + LO;
  float nz = 0x1.6a09e6p+0f * erfinv_giles(val);
  float q2 = nz * nz;
#pragma unroll
  for (int mm = 32; mm >= 1; mm >>= 1) q2 += __shfl_xor(q2, mm, 64);
  float nrm = __builtin_sqrtf(q2);
  float nh = nz / (nrm + 1e-12f);
  float sg = (x > 0.0f) ? 1.0f : ((x < 0.0f) ? -1.0f : 0.0f);
  x = x + sg * nh * 0.03f;

  // next-hop bf16 table (cached; skipped at last hop) + fp32 outputs (NT)
  if (HOP < 2) Tout[r * DIM + lane] = f2bf(x);
  constexpr int h1 = HOP + 1;
  if (r < N_USERS) {
    __builtin_nontemporal_store(x, &out[r * 256 + h1 * 64 + lane]);
    if (HOP == 0) __builtin_nontemporal_store(x, &out[OUT_CLU + r * 64 + lane]);
  } else {
    int i = r - N_USERS;
    __builtin_nontemporal_store(x, &out[OUT_I + i * 256 + h1 * 64 + lane]);
    if (HOP == 0) __builtin_nontemporal_store(x, &out[OUT_CLI + i * 64 + lane]);
  }
}

// ---------------- launch ----------------
extern "C" void kernel_launch(void* const* d_in, const int* in_sizes, int n_in,
                              void* d_out, int out_size, void* d_ws, size_t ws_size,
                              hipStream_t stream) {
  (void)in_sizes; (void)n_in; (void)out_size; (void)ws_size;
  const float* ue    = (const float*)d_in[0];
  const float* ie    = (const float*)d_in[1];
  const float* adjv  = (const float*)d_in[2];
  const float* gamma = (const float*)d_in[3];
  const float* beta  = (const float*)d_in[4];
  const int*   adji  = (const int*)d_in[5];
  const int* rows = adji;
  const int* cols = adji + NNZ;
  float* out = (float*)d_out;

  char* ws = (char*)d_ws;
  size_t off = 0;
  auto alloc = [&](size_t bytes) -> void* {
    void* p = ws + off;
    off += (bytes + 255) & ~(size_t)255;
    return p;
  };
  unsigned short* TA = (unsigned short*)alloc(sizeof(short) * NTOT * DIM);
  unsigned short* TB = (unsigned short*)alloc(sizeof(short) * NTOT * DIM);
  int*   gcount  = (int*)alloc(sizeof(int) * NB);
  int*   gtail   = (int*)alloc(sizeof(int) * 4);
  int2*  rowse3  = (int2*)alloc(sizeof(int2) * 3 * NTOT);
  uint2* staging = (uint2*)alloc(sizeof(uint2) * (size_t)NB * BCAP);
  uint2* packed3 = (uint2*)alloc(sizeof(uint2) * 3 * (size_t)HCAP);

  uint32_t K[3][6];
  for (uint32_t h = 0; h < 3; h++) {
    uint32_t h0, h1;
    tf2x32(0u, 42u, 0u, h, h0, h1);
    tf2x32(h0, h1, 0u, 0u, K[h][0], K[h][1]);  // ke
    tf2x32(h0, h1, 0u, 1u, K[h][2], K[h][3]);  // km
    tf2x32(h0, h1, 0u, 2u, K[h][4], K[h][5]);  // kp
  }

  (void)hipMemsetAsync(gcount, 0, sizeof(int) * NB, stream);
  (void)hipMemsetAsync(gtail, 0, sizeof(int) * 4, stream);

  const int nbInit = (NTOT * DIM / 4 + 255) / 256;
  k_bin_init<<<NBT + nbInit, 256, 0, stream>>>(rows, cols, adjv, gcount, staging,
                                               ue, ie, out, TA,
                                               K[0][0], K[0][1], K[1][0], K[1][1],
                                               K[2][0], K[2][1]);
  k_place3<<<NB, 256, 0, stream>>>(gcount, staging, packed3, rowse3, gtail);

  const int nbH = (NTOT * 64 + 255) / 256;
  k_hop<0><<<nbH, 256, 0, stream>>>(rowse3 + 0 * NTOT, packed3 + 0 * (size_t)HCAP,
                                    TA, TB, gamma, beta, out,
                                    K[0][2], K[0][3], K[0][4], K[0][5]);
  k_hop<1><<<nbH, 256, 0, stream>>>(rowse3 + 1 * NTOT, packed3 + 1 * (size_t)HCAP,
                                    TB, TA, gamma, beta, out,
                                    K[1][2], K[1][3], K[1][4], K[1][5]);
  k_hop<2><<<nbH, 256, 0, stream>>>(rowse3 + 2 * NTOT, packed3 + 2 * (size_t)HCAP,
                                    TA, nullptr, gamma, beta, out,
                                    K[2][2], K[2][3], K[2][4], K[2][5]);
}

// Round 17
// 614.869 us; speedup vs baseline: 1.0509x; 1.0324x over previous
//
#include <hip/hip_runtime.h>
#include <stdint.h>

// ---------------- problem constants ----------------
#define N_USERS 100000
#define N_ITEMS 200000
#define NTOT    300000
#define DIM     64
#define NNZ     4000000

// output layout (floats)
#define OUT_I    25600000   // after users embs  (100000*4*64)
#define OUT_CLU  76800000   // after items embs  (+200000*4*64)
#define OUT_CLI  83200000   // after users cl    (+100000*64)

#define COLMASK  0x7FFFFu   // 19 bits (NTOT < 524288)

// bucketed CSR build
#define RPB   1024                      // rows per bucket (rowlocal fits 10 bits)
#define NB    ((NTOT + RPB - 1) / RPB)  // 293
#define TILE  4096                      // edges per bin workgroup
#define NBT   ((NNZ + TILE - 1) / TILE) // 977 bin tiles
#define BCAP  20480                     // per-bucket staging capacity (mean 13.6K, 58 sigma)
#define HCAP  2500000                   // per-hop active-edge capacity (~2M + pads + margin)

typedef float floatx4 __attribute__((ext_vector_type(4)));
typedef uint32_t u32x4 __attribute__((ext_vector_type(4)));
typedef unsigned short ushortx4 __attribute__((ext_vector_type(4)));

// ---------------- threefry2x32 (20 rounds) ----------------
__host__ __device__ __forceinline__ void tf2x32(uint32_t k0, uint32_t k1,
                                                uint32_t x0, uint32_t x1,
                                                uint32_t& o0, uint32_t& o1) {
  uint32_t ks2 = k0 ^ k1 ^ 0x1BD11BDAu;
#define TFR(r) { x0 += x1; x1 = (x1 << (r)) | (x1 >> (32 - (r))); x1 ^= x0; }
  x0 += k0; x1 += k1;
  TFR(13) TFR(15) TFR(26) TFR(6)
  x0 += k1;  x1 += ks2 + 1u;
  TFR(17) TFR(29) TFR(16) TFR(24)
  x0 += ks2; x1 += k0 + 2u;
  TFR(13) TFR(15) TFR(26) TFR(6)
  x0 += k0;  x1 += k1 + 3u;
  TFR(17) TFR(29) TFR(16) TFR(24)
  x0 += k1;  x1 += ks2 + 4u;
  TFR(13) TFR(15) TFR(26) TFR(6)
  x0 += ks2; x1 += k0 + 5u;
#undef TFR
  o0 = x0; o1 = x1;
}

__device__ __forceinline__ uint32_t rnd_bits(uint32_t k0, uint32_t k1, uint32_t j) {
  uint32_t a, b;
  tf2x32(k0, k1, 0u, j, a, b);
  return a ^ b;
}

__device__ __forceinline__ float u01f(uint32_t bits) {
  return __uint_as_float((bits >> 9) | 0x3f800000u) - 1.0f;
}

// fp32 -> bf16 with round-to-nearest-even
__device__ __forceinline__ unsigned short f2bf(float f) {
  uint32_t u = __float_as_uint(f);
  return (unsigned short)((u + 0x7FFFu + ((u >> 16) & 1u)) >> 16);
}

// branchless single-precision erfinv (Giles 2010)
__device__ __forceinline__ float erfinv_giles(float x) {
  float w = -__logf((1.0f - x) * (1.0f + x));
  float wc = w - 2.5f;
  float p1 = 2.81022636e-08f;
  p1 = fmaf(p1, wc, 3.43273939e-07f);
  p1 = fmaf(p1, wc, -3.5233877e-06f);
  p1 = fmaf(p1, wc, -4.39150654e-06f);
  p1 = fmaf(p1, wc, 0.00021858087f);
  p1 = fmaf(p1, wc, -0.00125372503f);
  p1 = fmaf(p1, wc, -0.00417768164f);
  p1 = fmaf(p1, wc, 0.246640727f);
  p1 = fmaf(p1, wc, 1.50140941f);
  float wt = __builtin_sqrtf(w) - 3.0f;
  float p2 = -0.000200214257f;
  p2 = fmaf(p2, wt, 0.000100950558f);
  p2 = fmaf(p2, wt, 0.00134934322f);
  p2 = fmaf(p2, wt, -0.00367342844f);
  p2 = fmaf(p2, wt, 0.00573950773f);
  p2 = fmaf(p2, wt, -0.0076224613f);
  p2 = fmaf(p2, wt, 0.00943887047f);
  p2 = fmaf(p2, wt, 1.00167406f);
  p2 = fmaf(p2, wt, 2.83297682f);
  float p = (w < 5.0f) ? p1 : p2;
  return p * x;
}

// ---------------- scalar (SMEM) loads for wave-uniform data ----------------
// early-clobber (=&s) REQUIRED: outputs written while address input still live.
__device__ __forceinline__ void sload_se(const int2* p, int& s, int& e) {
  uint64_t r;
  asm volatile("s_load_dwordx2 %0, %1, 0x0\n\t"
               "s_waitcnt lgkmcnt(0)"
               : "=&s"(r) : "s"(p));
  s = (int)(uint32_t)r;
  e = (int)(uint32_t)(r >> 32);
}
// 8 records (64B)
__device__ __forceinline__ void sload_rec8(const uint2* p, u32x4& a, u32x4& b,
                                           u32x4& c, u32x4& d) {
  asm volatile("s_load_dwordx4 %0, %4, 0x0\n\t"
               "s_load_dwordx4 %1, %4, 0x10\n\t"
               "s_load_dwordx4 %2, %4, 0x20\n\t"
               "s_load_dwordx4 %3, %4, 0x30\n\t"
               "s_waitcnt lgkmcnt(0)"
               : "=&s"(a), "=&s"(b), "=&s"(c), "=&s"(d) : "s"(p));
}
// 6 records (48B)
__device__ __forceinline__ void sload_rec6(const uint2* p, u32x4& a, u32x4& b, u32x4& c) {
  asm volatile("s_load_dwordx4 %0, %3, 0x0\n\t"
               "s_load_dwordx4 %1, %3, 0x10\n\t"
               "s_load_dwordx4 %2, %3, 0x20\n\t"
               "s_waitcnt lgkmcnt(0)"
               : "=&s"(a), "=&s"(b), "=&s"(c) : "s"(p));
}
// 4 records (32B)
__device__ __forceinline__ void sload_rec4(const uint2* p, u32x4& a, u32x4& b) {
  asm volatile("s_load_dwordx4 %0, %2, 0x0\n\t"
               "s_load_dwordx4 %1, %2, 0x10\n\t"
               "s_waitcnt lgkmcnt(0)"
               : "=&s"(a), "=&s"(b) : "s"(p));
}
// 2 records (16B)
__device__ __forceinline__ void sload_rec2(const uint2* p, u32x4& a) {
  asm volatile("s_load_dwordx4 %0, %1, 0x0\n\t"
               "s_waitcnt lgkmcnt(0)"
               : "=&s"(a) : "s"(p));
}

// ---------------- phase 1 (merged): bin edges + init hop-0 outputs ----------
// blocks [0, NBT): bin; blocks [NBT, ...): out slot 0 + bf16 table build.
// staging record: w0 = col | m0<<19 | m1<<20 | m2<<21 | rowlocal<<22 ; w1 = val*2
__global__ __launch_bounds__(256) void k_bin_init(const int* __restrict__ rows,
                                                  const int* __restrict__ cols,
                                                  const float* __restrict__ adjv,
                                                  int* __restrict__ gcount,
                                                  uint2* __restrict__ staging,
                                                  const float* __restrict__ ue,
                                                  const float* __restrict__ ie,
                                                  float* __restrict__ out,
                                                  unsigned short* __restrict__ T0,
                                                  uint32_t ke00, uint32_t ke01,
                                                  uint32_t ke10, uint32_t ke11,
                                                  uint32_t ke20, uint32_t ke21) {
  __shared__ int hist[NB];
  __shared__ int gb[NB];
  if (blockIdx.x >= NBT) {
    // ---- init part: out slot 0 (fp32 NT) + bf16 gather table ----
    int t = (blockIdx.x - NBT) * 256 + threadIdx.x;
    if (t >= NTOT * DIM / 4) return;
    int j = t * 4;
    int r = j >> 6;
    int d = j & 63;
    floatx4 v = (r < N_USERS) ? *reinterpret_cast<const floatx4*>(ue + j)
                              : *reinterpret_cast<const floatx4*>(ie + (j - N_USERS * DIM));
    int o = (r < N_USERS) ? (r * 256 + d) : (OUT_I + (r - N_USERS) * 256 + d);
    __builtin_nontemporal_store(v, reinterpret_cast<floatx4*>(out + o));
    ushortx4 bv;
    bv.x = f2bf(v.x); bv.y = f2bf(v.y); bv.z = f2bf(v.z); bv.w = f2bf(v.w);
    *reinterpret_cast<ushortx4*>(T0 + j) = bv;
    return;
  }
  // ---- bin part ----
  int t = threadIdx.x;
  for (int i = t; i < NB; i += 256) hist[i] = 0;
  __syncthreads();
  int base = blockIdx.x * TILE;

  uint32_t recx[16];
  float    recy[16];
  uint32_t bl[16];   // (bucket<<13) | localpos, 0xFFFFFFFF = invalid

#pragma unroll
  for (int i = 0; i < 16; i++) {
    int e = base + i * 256 + t;
    bl[i] = 0xFFFFFFFFu;
    if (e < NNZ) {
      int r = rows[e];
      uint32_t c = (uint32_t)cols[e];
      uint32_t m0 = rnd_bits(ke00, ke01, (uint32_t)e) >> 31;
      uint32_t m1 = rnd_bits(ke10, ke11, (uint32_t)e) >> 31;
      uint32_t m2 = rnd_bits(ke20, ke21, (uint32_t)e) >> 31;
      recx[i] = c | (m0 << 19) | (m1 << 20) | (m2 << 21) | ((uint32_t)(r & (RPB - 1)) << 22);
      recy[i] = adjv[e] * 2.0f;
      int b = r >> 10;
      int lp = atomicAdd(&hist[b], 1);
      bl[i] = ((uint32_t)b << 13) | (uint32_t)lp;
    }
  }
  __syncthreads();
  for (int i = t; i < NB; i += 256) {
    int c = hist[i];
    gb[i] = c ? atomicAdd(&gcount[i], c) : 0;
  }
  __syncthreads();
#pragma unroll
  for (int i = 0; i < 16; i++) {
    if (bl[i] != 0xFFFFFFFFu) {
      int b  = (int)(bl[i] >> 13);
      int lp = (int)(bl[i] & 0x1FFFu);
      staging[(size_t)b * BCAP + gb[b] + lp] = make_uint2(recx[i], __float_as_uint(recy[i]));
    }
  }
}

// ---------------- phase 2: per-bucket count/scan/reserve/scatter ------------
__global__ __launch_bounds__(256) void k_place3(const int* __restrict__ gcount,
                                                const uint2* __restrict__ staging,
                                                uint2* __restrict__ packed3,
                                                int2* __restrict__ rowse3,
                                                int* __restrict__ gtail) {
  __shared__ int cnt[3][RPB];
  __shared__ int off[3][RPB];
  __shared__ int sm[256];
  __shared__ int gbh[3];
  int b = blockIdx.x;
  int t = threadIdx.x;
  int r0 = b << 10;
  for (int j = t; j < RPB; j += 256) { cnt[0][j] = 0; cnt[1][j] = 0; cnt[2][j] = 0; }
  __syncthreads();
  int ln = gcount[b];
  const uint2* run = staging + (size_t)b * BCAP;

  // pass A: per-row per-hop counts
  for (int i = t; i < ln; i += 256) {
    uint32_t w = run[i].x;
    int rl = (int)(w >> 22);
    if (w & (1u << 19)) atomicAdd(&cnt[0][rl], 1);
    if (w & (1u << 20)) atomicAdd(&cnt[1][rl], 1);
    if (w & (1u << 21)) atomicAdd(&cnt[2][rl], 1);
  }
  __syncthreads();

  // pass B: evened exclusive scan per hop + global reservation
  for (int h = 0; h < 3; h++) {
    int j0 = t * 4;
    int c0 = cnt[h][j0], c1 = cnt[h][j0 + 1], c2 = cnt[h][j0 + 2], c3 = cnt[h][j0 + 3];
    int e0 = (c0 + 1) & ~1, e1 = (c1 + 1) & ~1, e2 = (c2 + 1) & ~1, e3 = (c3 + 1) & ~1;
    int s4 = e0 + e1 + e2 + e3;
    sm[t] = s4;
    __syncthreads();
    for (int o2 = 1; o2 < 256; o2 <<= 1) {
      int y = (t >= o2) ? sm[t - o2] : 0;
      __syncthreads();
      sm[t] += y;
      __syncthreads();
    }
    int ex = sm[t] - s4;
    off[h][j0]     = ex;
    off[h][j0 + 1] = ex + e0;
    off[h][j0 + 2] = ex + e0 + e1;
    off[h][j0 + 3] = ex + e0 + e1 + e2;
    if (t == 255) gbh[h] = atomicAdd(&gtail[h], sm[255]);
    __syncthreads();
  }

  // pass B2: rowse + pad records + absolute fill positions
  int nr = min(RPB, NTOT - r0);
  for (int h = 0; h < 3; h++) {
    int gb = gbh[h];
    for (int j = t; j < RPB; j += 256) {
      int raw = cnt[h][j];
      int start = gb + off[h][j];
      off[h][j] = start;  // absolute scatter cursor
      if (j < nr) {
        rowse3[h * NTOT + r0 + j] = make_int2(start, start + ((raw + 1) & ~1));
        if (raw & 1) packed3[(size_t)h * HCAP + start + raw] = make_uint2(0u, 0u);
      }
    }
  }
  __syncthreads();

  // pass C: scatter records to per-hop lists
  for (int i = t; i < ln; i += 256) {
    uint2 rec = run[i];
    int rl = (int)(rec.x >> 22);
    uint2 orec = make_uint2(rec.x & COLMASK, rec.y);
    if (rec.x & (1u << 19)) { int p = atomicAdd(&off[0][rl], 1); packed3[0 * (size_t)HCAP + p] = orec; }
    if (rec.x & (1u << 20)) { int p = atomicAdd(&off[1][rl], 1); packed3[1 * (size_t)HCAP + p] = orec; }
    if (rec.x & (1u << 21)) { int p = atomicAdd(&off[2][rl], 1); packed3[2 * (size_t)HCAP + p] = orec; }
  }
}

// ---------------- fused hop: SpMM + LN + dropout + perturb + outputs --------
// one 64-lane wave per row. DUAL-EDGE gather: lanes 0-31 fetch edge A's row,
// lanes 32-63 edge B's; each lane loads a dword (2 bf16 dims) -> one gather
// instruction per TWO edges. shfl_xor(32) combines, 2 shuffles redistribute
// dims to 1/lane for the unchanged post-math.
template <int HOP>
__global__ __launch_bounds__(256) void k_hop(const int2* __restrict__ rowse,
                                             const uint2* __restrict__ packed,
                                             const unsigned short* __restrict__ Tin,
                                             unsigned short* __restrict__ Tout,
                                             const float* __restrict__ gamma,
                                             const float* __restrict__ beta,
                                             float* __restrict__ out,
                                             uint32_t km0, uint32_t km1,
                                             uint32_t kp0, uint32_t kp1) {
  int lane = threadIdx.x & 63;
  bool hi = lane >= 32;
  int l31 = lane & 31;
  int r = __builtin_amdgcn_readfirstlane((int)(blockIdx.x * blockDim.x + threadIdx.x) >> 6);
  if (r >= NTOT) return;
  int s, e;
  sload_se(rowse + r, s, e);
  s = max(s, 0);
  e = min(e, HCAP);
  const uint32_t* __restrict__ T32 = (const uint32_t*)Tin;

  // per-pair: cc = col of (hi? edge B : edge A); load dword = dims {2*l31, 2*l31+1}
#define PAIR(q, alo, ahi) {                                                     \
    uint32_t cc = hi ? (uint32_t)q.z : (uint32_t)q.x;                           \
    uint32_t vv = hi ? (uint32_t)q.w : (uint32_t)q.y;                           \
    uint32_t u = T32[cc * 32 + l31];                                            \
    float vf = __uint_as_float(vv);                                             \
    alo = fmaf(vf, __uint_as_float(u << 16), alo);                              \
    ahi = fmaf(vf, __uint_as_float(u & 0xFFFF0000u), ahi); }

  float lo0 = 0.0f, hi0 = 0.0f, lo1 = 0.0f, hi1 = 0.0f;
  int k = s;
  for (; k + 7 < e; k += 8) {
    u32x4 qa, qb, qc, qd;
    sload_rec8(packed + k, qa, qb, qc, qd);
    PAIR(qa, lo0, hi0) PAIR(qb, lo1, hi1)
    PAIR(qc, lo0, hi0) PAIR(qd, lo1, hi1)
  }
  {
    int rem = e - k;   // even: 0,2,4,6
    u32x4 qa, qb, qc;
    if (rem == 6) { sload_rec6(packed + k, qa, qb, qc); PAIR(qa, lo0, hi0) PAIR(qb, lo1, hi1) PAIR(qc, lo0, hi0) }
    else if (rem == 4) { sload_rec4(packed + k, qa, qb); PAIR(qa, lo0, hi0) PAIR(qb, lo1, hi1) }
    else if (rem == 2) { sload_rec2(packed + k, qa); PAIR(qa, lo0, hi0) }
  }
#undef PAIR

  float alo = lo0 + lo1;
  float ahi = hi0 + hi1;
  // combine even-edge (lanes<32) and odd-edge (lanes>=32) partial sums
  alo += __shfl_xor(alo, 32, 64);
  ahi += __shfl_xor(ahi, 32, 64);
  // redistribute: lane d owns dim d ( = slot d&1 of lane d>>1 )
  float xlo = __shfl(alo, lane >> 1, 64);
  float xhi = __shfl(ahi, lane >> 1, 64);
  float x = (lane & 1) ? xhi : xlo;

  // layer norm: fused dual reduction (sum, sumsq) over the wave
  float s1 = x, s2 = x * x;
#pragma unroll
  for (int mm = 32; mm >= 1; mm >>= 1) {
    s1 += __shfl_xor(s1, mm, 64);
    s2 += __shfl_xor(s2, mm, 64);
  }
  float mu = s1 * (1.0f / 64.0f);
  float var = fmaxf(s2 * (1.0f / 64.0f) - mu * mu, 0.0f);
  x = (x - mu) * rsqrtf(var + 1e-5f) * gamma[lane] + beta[lane];

  // message dropout: keep iff uniform >= 0.1
  uint32_t j = (uint32_t)(r * DIM + lane);
  float um = u01f(rnd_bits(km0, km1, j));
  const float INV_KEEP = (float)(1.0 / 0.9);
  x = x * ((um >= 0.1f) ? INV_KEEP : 0.0f);

  // perturbation: normal via erfinv of uniform(lo, 1), row-normalized
  float un = u01f(rnd_bits(kp0, kp1, j));
  const float LO = __uint_as_float(0xBF7FFFFFu);
  float val = un * 2.0f + LO;
  float nz = 0x1.6a09e6p+0f * erfinv_giles(val);
  float q2 = nz * nz;
#pragma unroll
  for (int mm = 32; mm >= 1; mm >>= 1) q2 += __shfl_xor(q2, mm, 64);
  float nrm = __builtin_sqrtf(q2);
  float nh = nz / (nrm + 1e-12f);
  float sg = (x > 0.0f) ? 1.0f : ((x < 0.0f) ? -1.0f : 0.0f);
  x = x + sg * nh * 0.03f;

  // next-hop bf16 table (cached; skipped at last hop) + fp32 outputs (NT)
  if (HOP < 2) Tout[r * DIM + lane] = f2bf(x);
  constexpr int h1 = HOP + 1;
  if (r < N_USERS) {
    __builtin_nontemporal_store(x, &out[r * 256 + h1 * 64 + lane]);
    if (HOP == 0) __builtin_nontemporal_store(x, &out[OUT_CLU + r * 64 + lane]);
  } else {
    int i = r - N_USERS;
    __builtin_nontemporal_store(x, &out[OUT_I + i * 256 + h1 * 64 + lane]);
    if (HOP == 0) __builtin_nontemporal_store(x, &out[OUT_CLI + i * 64 + lane]);
  }
}

// ---------------- launch ----------------
extern "C" void kernel_launch(void* const* d_in, const int* in_sizes, int n_in,
                              void* d_out, int out_size, void* d_ws, size_t ws_size,
                              hipStream_t stream) {
  (void)in_sizes; (void)n_in; (void)out_size; (void)ws_size;
  const float* ue    = (const float*)d_in[0];
  const float* ie    = (const float*)d_in[1];
  const float* adjv  = (const float*)d_in[2];
  const float* gamma = (const float*)d_in[3];
  const float* beta  = (const float*)d_in[4];
  const int*   adji  = (const int*)d_in[5];
  const int* rows = adji;
  const int* cols = adji + NNZ;
  float* out = (float*)d_out;

  char* ws = (char*)d_ws;
  size_t off = 0;
  auto alloc = [&](size_t bytes) -> void* {
    void* p = ws + off;
    off += (bytes + 255) & ~(size_t)255;
    return p;
  };
  unsigned short* TA = (unsigned short*)alloc(sizeof(short) * NTOT * DIM);
  unsigned short* TB = (unsigned short*)alloc(sizeof(short) * NTOT * DIM);
  int*   gcount  = (int*)alloc(sizeof(int) * NB);
  int*   gtail   = (int*)alloc(sizeof(int) * 4);
  int2*  rowse3  = (int2*)alloc(sizeof(int2) * 3 * NTOT);
  uint2* staging = (uint2*)alloc(sizeof(uint2) * (size_t)NB * BCAP);
  uint2* packed3 = (uint2*)alloc(sizeof(uint2) * 3 * (size_t)HCAP);

  // host-side key derivation: kh = fold_in(key(42), hop); (ke,km,kp) = split(kh, 3)
  uint32_t K[3][6];
  for (uint32_t h = 0; h < 3; h++) {
    uint32_t h0, h1;
    tf2x32(0u, 42u, 0u, h, h0, h1);
    tf2x32(h0, h1, 0u, 0u, K[h][0], K[h][1]);  // ke
    tf2x32(h0, h1, 0u, 1u, K[h][2], K[h][3]);  // km
    tf2x32(h0, h1, 0u, 2u, K[h][4], K[h][5]);  // kp
  }

  (void)hipMemsetAsync(gcount, 0, sizeof(int) * NB, stream);
  (void)hipMemsetAsync(gtail, 0, sizeof(int) * 4, stream);

  const int nbInit = (NTOT * DIM / 4 + 255) / 256;  // 18750
  k_bin_init<<<NBT + nbInit, 256, 0, stream>>>(rows, cols, adjv, gcount, staging,
                                               ue, ie, out, TA,
                                               K[0][0], K[0][1], K[1][0], K[1][1],
                                               K[2][0], K[2][1]);
  k_place3<<<NB, 256, 0, stream>>>(gcount, staging, packed3, rowse3, gtail);

  const int nbH = (NTOT * DIM + 255) / 256;
  // hop 0: TA -> TB
  k_hop<0><<<nbH, 256, 0, stream>>>(rowse3 + 0 * NTOT, packed3 + 0 * (size_t)HCAP,
                                    TA, TB, gamma, beta, out,
                                    K[0][2], K[0][3], K[0][4], K[0][5]);
  // hop 1: TB -> TA
  k_hop<1><<<nbH, 256, 0, stream>>>(rowse3 + 1 * NTOT, packed3 + 1 * (size_t)HCAP,
                                    TB, TA, gamma, beta, out,
                                    K[1][2], K[1][3], K[1][4], K[1][5]);
  // hop 2: TA -> outputs only
  k_hop<2><<<nbH, 256, 0, stream>>>(rowse3 + 2 * NTOT, packed3 + 2 * (size_t)HCAP,
                                    TA, nullptr, gamma, beta, out,
                                    K[2][2], K[2][3], K[2][4], K[2][5]);
}